// Round 7
// baseline (278.311 us; speedup 1.0000x reference)
//
#include <hip/hip_runtime.h>

// EMA y_t = w*x_t + (1-w)*y_{t-1}, a = 1-w per-channel constant.
// SINGLE fused kernel, chunk length L=64, P = T/L = 128 chunks per batch row.
// Decoupled lookback. Sync discipline (hard-won over 6 rounds):
//   - Spin ONLY on flags (relaxed agent-scope u32 loads) — proven R1/R3/R4.
//     Both attempts to spin directly on sentinel data hung (R2, R6).
//   - Aggregates published as relaxed agent-scope (sc1) u64 stores, then
//     s_waitcnt vmcnt(0), THEN the flag store: flag observed => data at the
//     coherence point, so sentinel-validation retries are near-never taken.
//   - Sentinel validation (0xFF..F = two -NaNs, unreachable from finite FMA)
//     still backs correctness; flags are only a performance gate.
//   - ZERO fences / cache-maintenance ops (R1: per-iter acquire = 366us;
//     R3: even one wbl2+inv per block = XCD-wide flush storm, 157us).
// R4 measured 108us @ 4% VALUBusy: residual cost was the flag spin polling
// all p flags (~8 lines) per iteration -> ~0.5 GB of sc1 line requests.
// THIS round: gate each 8-row batch on ONE wave-uniform flag (flag[q+7],
// one 64B line per poll, s_sleep(16)), tail rows on flag[q]. ~13 MB total
// poll traffic. Batch consumption now overlaps waiting (per-batch gates
// instead of all-flags-first).

#define CHUNK_L 64
#define SENTI64 0xFFFFFFFFFFFFFFFFull

__device__ __forceinline__ float clip01(float v) {
    return fminf(fmaxf(v, 0.0f), 1.0f);
}

__global__ __launch_bounds__(64) void ema_fused(
    const float* __restrict__ x, const float* __restrict__ smooth,
    const float* __restrict__ init, float* __restrict__ out,
    float* __restrict__ chunk_last, unsigned int* __restrict__ flags,
    int T, int C, int P) {
    const int blk = blockIdx.x;          // b*P + p
    const int b = blk / P;
    const int p = blk - b * P;
    const int t = threadIdx.x;
    const int c = t << 2;

    float4 w4 = *(const float4*)(smooth + c);
    w4.x = clip01(w4.x); w4.y = clip01(w4.y); w4.z = clip01(w4.z); w4.w = clip01(w4.w);
    const float ax = 1.0f - w4.x, ay = 1.0f - w4.y, az = 1.0f - w4.z, aw = 1.0f - w4.w;

    const int sF4 = C >> 2;
    const size_t base = ((size_t)b * T + (size_t)p * CHUNK_L) * C;
    const float4* xp = (const float4*)(x + base) + t;

    // ---- phase A: zero-seeded local scan -> chunk aggregate ----
    float y0 = 0.0f, y1 = 0.0f, y2 = 0.0f, y3 = 0.0f;
    for (int i0 = 0; i0 < CHUNK_L; i0 += 8) {
        float4 xv[8];
#pragma unroll
        for (int j = 0; j < 8; ++j) xv[j] = xp[(size_t)(i0 + j) * sF4];
#pragma unroll
        for (int j = 0; j < 8; ++j) {
            y0 = fmaf(ax, y0, w4.x * xv[j].x);
            y1 = fmaf(ay, y1, w4.y * xv[j].y);
            y2 = fmaf(az, y2, w4.z * xv[j].z);
            y3 = fmaf(aw, y3, w4.w * xv[j].w);
        }
    }
    // Publish aggregate via relaxed agent-scope (sc1) u64 stores.
    {
        union { float f[4]; unsigned long long u[2]; } r;
        r.f[0] = y0; r.f[1] = y1; r.f[2] = y2; r.f[3] = y3;
        unsigned long long* dst =
            (unsigned long long*)(chunk_last + (size_t)blk * C + c);
        __hip_atomic_store(dst + 0, r.u[0], __ATOMIC_RELAXED, __HIP_MEMORY_SCOPE_AGENT);
        __hip_atomic_store(dst + 1, r.u[1], __ATOMIC_RELAXED, __HIP_MEMORY_SCOPE_AGENT);
    }
    // Wave-local drain: data reaches the coherence point before the flag.
    asm volatile("s_waitcnt vmcnt(0)" ::: "memory");
    if (t == 0) {
        __hip_atomic_store(flags + blk, 1u, __ATOMIC_RELAXED, __HIP_MEMORY_SCOPE_AGENT);
    }

    // aL = a^CHUNK_L by repeated squaring (6 squarings for L=64)
    float aLx = ax, aLy = ay, aLz = az, aLw = aw;
    for (int e = CHUNK_L; e > 1; e >>= 1) { aLx *= aLx; aLy *= aLy; aLz *= aLz; aLw *= aLw; }

    // ---- carry-in: per-batch flag gate + sentinel-validated sc1 lookback ----
    float4 s = *(const float4*)(init + (size_t)b * C + c);
    if (p > 0) {
        const unsigned int* fl = flags + (size_t)b * P;
        const unsigned long long* cl =
            (const unsigned long long*)(chunk_last + (size_t)b * P * C) + (t << 1);
        const int sU64 = C >> 1;              // u64 stride per chunk row

        int q = 0;
        for (; q + 8 <= p; q += 8) {
            // Gate: ONE wave-uniform flag (one 64B line per poll).
            while (__hip_atomic_load(fl + (q + 7), __ATOMIC_RELAXED,
                                     __HIP_MEMORY_SCOPE_AGENT) == 0u) {
                __builtin_amdgcn_s_sleep(16);
            }
            // Batch load + per-word sentinel validation (near-never retried:
            // producers drain data before flags; stragglers q..q+6 covered).
            union { float f[4]; unsigned long long u[2]; } l[8];
            for (;;) {
                bool ok = true;
#pragma unroll
                for (int j = 0; j < 8; ++j) {
                    const unsigned long long* src = cl + (size_t)(q + j) * sU64;
                    l[j].u[0] = __hip_atomic_load(src + 0, __ATOMIC_RELAXED,
                                                  __HIP_MEMORY_SCOPE_AGENT);
                    l[j].u[1] = __hip_atomic_load(src + 1, __ATOMIC_RELAXED,
                                                  __HIP_MEMORY_SCOPE_AGENT);
                    ok &= (l[j].u[0] != SENTI64) & (l[j].u[1] != SENTI64);
                }
                if (__all((int)ok)) break;
                __builtin_amdgcn_s_sleep(2);
            }
#pragma unroll
            for (int j = 0; j < 8; ++j) {
                s.x = fmaf(aLx, s.x, l[j].f[0]);
                s.y = fmaf(aLy, s.y, l[j].f[1]);
                s.z = fmaf(aLz, s.z, l[j].f[2]);
                s.w = fmaf(aLw, s.w, l[j].f[3]);
            }
        }
        for (; q < p; ++q) {
            while (__hip_atomic_load(fl + q, __ATOMIC_RELAXED,
                                     __HIP_MEMORY_SCOPE_AGENT) == 0u) {
                __builtin_amdgcn_s_sleep(8);
            }
            union { float f[4]; unsigned long long u[2]; } l;
            const unsigned long long* src = cl + (size_t)q * sU64;
            for (;;) {
                l.u[0] = __hip_atomic_load(src + 0, __ATOMIC_RELAXED,
                                           __HIP_MEMORY_SCOPE_AGENT);
                l.u[1] = __hip_atomic_load(src + 1, __ATOMIC_RELAXED,
                                           __HIP_MEMORY_SCOPE_AGENT);
                if (__all((int)((l.u[0] != SENTI64) & (l.u[1] != SENTI64)))) break;
                __builtin_amdgcn_s_sleep(2);
            }
            s.x = fmaf(aLx, s.x, l.f[0]);
            s.y = fmaf(aLy, s.y, l.f[1]);
            s.z = fmaf(aLz, s.z, l.f[2]);
            s.w = fmaf(aLw, s.w, l.f[3]);
        }
    }

    // ---- phase B: re-stream this chunk seeded with s (x L2/MALL-warm) ----
    float4* op = (float4*)(out + base) + t;
    float yb0 = s.x, yb1 = s.y, yb2 = s.z, yb3 = s.w;
    for (int i0 = 0; i0 < CHUNK_L; i0 += 8) {
        float4 xv[8];
#pragma unroll
        for (int j = 0; j < 8; ++j) xv[j] = xp[(size_t)(i0 + j) * sF4];
#pragma unroll
        for (int j = 0; j < 8; ++j) {
            yb0 = fmaf(ax, yb0, w4.x * xv[j].x);
            yb1 = fmaf(ay, yb1, w4.y * xv[j].y);
            yb2 = fmaf(az, yb2, w4.z * xv[j].z);
            yb3 = fmaf(aw, yb3, w4.w * xv[j].w);
            float4 r; r.x = yb0; r.y = yb1; r.z = yb2; r.w = yb3;
            op[(size_t)(i0 + j) * sF4] = r;
        }
    }
}

extern "C" void kernel_launch(void* const* d_in, const int* in_sizes, int n_in,
                              void* d_out, int out_size, void* d_ws, size_t ws_size,
                              hipStream_t stream) {
    const float* x      = (const float*)d_in[0];  // [B, T, C]
    const float* init   = (const float*)d_in[1];  // [B, C]
    const float* smooth = (const float*)d_in[2];  // [C]
    float* out = (float*)d_out;

    const int C  = in_sizes[2];
    const int BC = in_sizes[1];
    const int B  = BC / C;
    const int T  = in_sizes[0] / BC;
    const int P  = T / CHUNK_L;

    float* chunk_last = (float*)d_ws;                               // [B, P, C]
    unsigned int* flags =
        (unsigned int*)((char*)d_ws + (size_t)B * P * C * sizeof(float));  // [B*P]

    // Workspace is poisoned each iteration. Byte-pattern hipMemsetAsync only
    // (capture-proven): chunk_last -> 0xFF sentinel (2MB), flags -> 0 (8KB).
    (void)hipMemsetAsync(chunk_last, 0xFF, (size_t)B * P * C * sizeof(float), stream);
    (void)hipMemsetAsync(flags, 0, (size_t)B * P * sizeof(unsigned int), stream);

    ema_fused<<<dim3(B * P), dim3(C / 4), 0, stream>>>(
        x, smooth, init, out, chunk_last, flags, T, C, P);
}

// Round 8
// 259.159 us; speedup vs baseline: 1.0739x; 1.0739x over previous
//
#include <hip/hip_runtime.h>

// EMA y_t = w*x_t + (1-w)*y_{t-1}, a = 1-w per-channel constant.
// SINGLE fused kernel, chunk length L=256, P = T/L = 32 chunks per batch row.
// Decoupled lookback. Sync discipline (proven over 7 rounds):
//   - Spin ONLY on flags (relaxed agent-scope u32) — proven R1/R3/R4/R7.
//     Spinning directly on sentinel data hung twice (R2, R6). Never again.
//   - Aggregates published as relaxed agent-scope (sc1) u64 stores, then
//     s_waitcnt vmcnt(0), THEN the flag store (data precedes flag).
//   - Sentinel validation (0xFF..F) backs correctness; flags are a gate.
//   - ZERO fences / cache-maintenance ops (R1/R3 lessons: wbl2/inv storms).
//
// R7 falsified the poll-storm theory (40x less poll traffic, same 111 us).
// Remaining suspect: the lookback DATA plane — at P=128 it was B*P^2/2 row
// re-reads = 134 MB of sc1 MALL traffic bursting right after phase A.
// THIS round: L 64->256, P 128->32. Lookback traffic drops 16x to ~8 MB,
// sync events 2048->512, max lookback depth 127->31 rows. Streaming phases
// are P-independent; with only 2 waves/CU now, load batches deepen 8->16
// (16 KiB in flight per wave) to stay HBM-bound on pure MLP.
// If this STILL lands ~110 us, the lookback is exonerated and the limiter
// is the streaming structure itself.

#define CHUNK_L 256
#define SENTI64 0xFFFFFFFFFFFFFFFFull

__device__ __forceinline__ float clip01(float v) {
    return fminf(fmaxf(v, 0.0f), 1.0f);
}

__global__ __launch_bounds__(64) void ema_fused(
    const float* __restrict__ x, const float* __restrict__ smooth,
    const float* __restrict__ init, float* __restrict__ out,
    float* __restrict__ chunk_last, unsigned int* __restrict__ flags,
    int T, int C, int P) {
    const int blk = blockIdx.x;          // b*P + p
    const int b = blk / P;
    const int p = blk - b * P;
    const int t = threadIdx.x;
    const int c = t << 2;

    float4 w4 = *(const float4*)(smooth + c);
    w4.x = clip01(w4.x); w4.y = clip01(w4.y); w4.z = clip01(w4.z); w4.w = clip01(w4.w);
    const float ax = 1.0f - w4.x, ay = 1.0f - w4.y, az = 1.0f - w4.z, aw = 1.0f - w4.w;

    const int sF4 = C >> 2;
    const size_t base = ((size_t)b * T + (size_t)p * CHUNK_L) * C;
    const float4* xp = (const float4*)(x + base) + t;

    // ---- phase A: zero-seeded local scan -> chunk aggregate ----
    float y0 = 0.0f, y1 = 0.0f, y2 = 0.0f, y3 = 0.0f;
    for (int i0 = 0; i0 < CHUNK_L; i0 += 16) {
        float4 xv[16];
#pragma unroll
        for (int j = 0; j < 16; ++j) xv[j] = xp[(size_t)(i0 + j) * sF4];
#pragma unroll
        for (int j = 0; j < 16; ++j) {
            y0 = fmaf(ax, y0, w4.x * xv[j].x);
            y1 = fmaf(ay, y1, w4.y * xv[j].y);
            y2 = fmaf(az, y2, w4.z * xv[j].z);
            y3 = fmaf(aw, y3, w4.w * xv[j].w);
        }
    }
    // Publish aggregate via relaxed agent-scope (sc1) u64 stores.
    {
        union { float f[4]; unsigned long long u[2]; } r;
        r.f[0] = y0; r.f[1] = y1; r.f[2] = y2; r.f[3] = y3;
        unsigned long long* dst =
            (unsigned long long*)(chunk_last + (size_t)blk * C + c);
        __hip_atomic_store(dst + 0, r.u[0], __ATOMIC_RELAXED, __HIP_MEMORY_SCOPE_AGENT);
        __hip_atomic_store(dst + 1, r.u[1], __ATOMIC_RELAXED, __HIP_MEMORY_SCOPE_AGENT);
    }
    // Wave-local drain: data reaches the coherence point before the flag.
    asm volatile("s_waitcnt vmcnt(0)" ::: "memory");
    if (t == 0) {
        __hip_atomic_store(flags + blk, 1u, __ATOMIC_RELAXED, __HIP_MEMORY_SCOPE_AGENT);
    }

    // aL = a^CHUNK_L by repeated squaring (8 squarings for L=256)
    float aLx = ax, aLy = ay, aLz = az, aLw = aw;
    for (int e = CHUNK_L; e > 1; e >>= 1) { aLx *= aLx; aLy *= aLy; aLz *= aLz; aLw *= aLw; }

    // ---- carry-in: per-batch flag gate + sentinel-validated sc1 lookback ----
    float4 s = *(const float4*)(init + (size_t)b * C + c);
    if (p > 0) {
        const unsigned int* fl = flags + (size_t)b * P;
        const unsigned long long* cl =
            (const unsigned long long*)(chunk_last + (size_t)b * P * C) + (t << 1);
        const int sU64 = C >> 1;              // u64 stride per chunk row

        int q = 0;
        for (; q + 8 <= p; q += 8) {
            // Gate: ONE wave-uniform flag (one 64B line per poll).
            while (__hip_atomic_load(fl + (q + 7), __ATOMIC_RELAXED,
                                     __HIP_MEMORY_SCOPE_AGENT) == 0u) {
                __builtin_amdgcn_s_sleep(16);
            }
            union { float f[4]; unsigned long long u[2]; } l[8];
            for (;;) {
                bool ok = true;
#pragma unroll
                for (int j = 0; j < 8; ++j) {
                    const unsigned long long* src = cl + (size_t)(q + j) * sU64;
                    l[j].u[0] = __hip_atomic_load(src + 0, __ATOMIC_RELAXED,
                                                  __HIP_MEMORY_SCOPE_AGENT);
                    l[j].u[1] = __hip_atomic_load(src + 1, __ATOMIC_RELAXED,
                                                  __HIP_MEMORY_SCOPE_AGENT);
                    ok &= (l[j].u[0] != SENTI64) & (l[j].u[1] != SENTI64);
                }
                if (__all((int)ok)) break;
                __builtin_amdgcn_s_sleep(2);
            }
#pragma unroll
            for (int j = 0; j < 8; ++j) {
                s.x = fmaf(aLx, s.x, l[j].f[0]);
                s.y = fmaf(aLy, s.y, l[j].f[1]);
                s.z = fmaf(aLz, s.z, l[j].f[2]);
                s.w = fmaf(aLw, s.w, l[j].f[3]);
            }
        }
        for (; q < p; ++q) {
            while (__hip_atomic_load(fl + q, __ATOMIC_RELAXED,
                                     __HIP_MEMORY_SCOPE_AGENT) == 0u) {
                __builtin_amdgcn_s_sleep(8);
            }
            union { float f[4]; unsigned long long u[2]; } l;
            const unsigned long long* src = cl + (size_t)q * sU64;
            for (;;) {
                l.u[0] = __hip_atomic_load(src + 0, __ATOMIC_RELAXED,
                                           __HIP_MEMORY_SCOPE_AGENT);
                l.u[1] = __hip_atomic_load(src + 1, __ATOMIC_RELAXED,
                                           __HIP_MEMORY_SCOPE_AGENT);
                if (__all((int)((l.u[0] != SENTI64) & (l.u[1] != SENTI64)))) break;
                __builtin_amdgcn_s_sleep(2);
            }
            s.x = fmaf(aLx, s.x, l.f[0]);
            s.y = fmaf(aLy, s.y, l.f[1]);
            s.z = fmaf(aLz, s.z, l.f[2]);
            s.w = fmaf(aLw, s.w, l.f[3]);
        }
    }

    // ---- phase B: re-stream this chunk seeded with s (x L2/MALL-warm) ----
    float4* op = (float4*)(out + base) + t;
    float yb0 = s.x, yb1 = s.y, yb2 = s.z, yb3 = s.w;
    for (int i0 = 0; i0 < CHUNK_L; i0 += 16) {
        float4 xv[16];
#pragma unroll
        for (int j = 0; j < 16; ++j) xv[j] = xp[(size_t)(i0 + j) * sF4];
#pragma unroll
        for (int j = 0; j < 16; ++j) {
            yb0 = fmaf(ax, yb0, w4.x * xv[j].x);
            yb1 = fmaf(ay, yb1, w4.y * xv[j].y);
            yb2 = fmaf(az, yb2, w4.z * xv[j].z);
            yb3 = fmaf(aw, yb3, w4.w * xv[j].w);
            float4 r; r.x = yb0; r.y = yb1; r.z = yb2; r.w = yb3;
            op[(size_t)(i0 + j) * sF4] = r;
        }
    }
}

extern "C" void kernel_launch(void* const* d_in, const int* in_sizes, int n_in,
                              void* d_out, int out_size, void* d_ws, size_t ws_size,
                              hipStream_t stream) {
    const float* x      = (const float*)d_in[0];  // [B, T, C]
    const float* init   = (const float*)d_in[1];  // [B, C]
    const float* smooth = (const float*)d_in[2];  // [C]
    float* out = (float*)d_out;

    const int C  = in_sizes[2];
    const int BC = in_sizes[1];
    const int B  = BC / C;
    const int T  = in_sizes[0] / BC;
    const int P  = T / CHUNK_L;

    float* chunk_last = (float*)d_ws;                               // [B, P, C]
    unsigned int* flags =
        (unsigned int*)((char*)d_ws + (size_t)B * P * C * sizeof(float));  // [B*P]

    // Workspace is poisoned each iteration. Byte-pattern hipMemsetAsync only
    // (capture-proven): chunk_last -> 0xFF sentinel (512KB), flags -> 0 (2KB).
    (void)hipMemsetAsync(chunk_last, 0xFF, (size_t)B * P * C * sizeof(float), stream);
    (void)hipMemsetAsync(flags, 0, (size_t)B * P * sizeof(unsigned int), stream);

    ema_fused<<<dim3(B * P), dim3(C / 4), 0, stream>>>(
        x, smooth, init, out, chunk_last, flags, T, C, P);
}